// Round 1
// baseline (5828.237 us; speedup 1.0000x reference)
//
#include <hip/hip_runtime.h>
#include <stdint.h>

// Problem constants
#define B_  64
#define S_  512
#define D_  1024
#define H_  1024

// Stage-2 partitioning
#define NBLK2 32           // persistent blocks (co-resident: 32 <= 256 CUs)
#define HC    32           // columns per block
#define NI    2            // HC/16 n-tiles per wave

typedef __attribute__((ext_vector_type(4))) float    f32x4;
typedef __attribute__((ext_vector_type(4))) uint32_t u32x4;
typedef __attribute__((ext_vector_type(8))) __bf16   bf16x8;

__device__ __forceinline__ f32x4 mfma16(bf16x8 a, bf16x8 b, f32x4 c) {
  return __builtin_amdgcn_mfma_f32_16x16x32_bf16(a, b, c, 0, 0, 0);
}

__device__ __forceinline__ void gload_lds16(const void* g, void* l) {
  __builtin_amdgcn_global_load_lds(
      (const __attribute__((address_space(1))) void*)g,
      (__attribute__((address_space(3))) void*)l, 16, 0, 0);
}

// pack hi16 of two f32 into one u32 (elem0 -> low half)
__device__ __forceinline__ uint32_t permhi(uint32_t hi_src, uint32_t lo_src) {
  return __builtin_amdgcn_perm(hi_src, lo_src, 0x07060302u);
}

// 8 fp32 -> (hi, lo) bf16x8 via truncation split: f == hi + lo (to ~2^-17 rel)
__device__ __forceinline__ void split8(f32x4 a0, f32x4 a1, bf16x8& hi, bf16x8& lo) {
  float f[8] = {a0.x, a0.y, a0.z, a0.w, a1.x, a1.y, a1.z, a1.w};
  uint32_t hb[8], lb[8];
#pragma unroll
  for (int i = 0; i < 8; ++i) {
    uint32_t b = __builtin_bit_cast(uint32_t, f[i]);
    hb[i] = b;
    float hf = __builtin_bit_cast(float, b & 0xffff0000u);
    lb[i] = __builtin_bit_cast(uint32_t, f[i] - hf);
  }
  u32x4 hv = {permhi(hb[1], hb[0]), permhi(hb[3], hb[2]),
              permhi(hb[5], hb[4]), permhi(hb[7], hb[6])};
  u32x4 lv = {permhi(lb[1], lb[0]), permhi(lb[3], lb[2]),
              permhi(lb[5], lb[4]), permhi(lb[7], lb[6])};
  hi = __builtin_bit_cast(bf16x8, hv);
  lo = __builtin_bit_cast(bf16x8, lv);
}

// ---------------------------------------------------------------------------
// prep: WxT/WhT = transpose + hi/lo bf16 split of Wx, Wh.  Also zero barrier cnt.
// grid 2048 x 256: bid<1024 -> Wx, else Wh; 32x32 tiles via LDS.
// ---------------------------------------------------------------------------
__global__ __launch_bounds__(256) void prep_kernel(
    const float* __restrict__ Wx, const float* __restrict__ Wh,
    uint16_t* __restrict__ wxt_hi, uint16_t* __restrict__ wxt_lo,
    uint16_t* __restrict__ wht_hi, uint16_t* __restrict__ wht_lo,
    unsigned* __restrict__ cnt)
{
  if (blockIdx.x == 0 && threadIdx.x == 0) *cnt = 0u;
  __shared__ float tile[32][33];
  int bid = blockIdx.x;
  int mat = bid >> 10;
  int t   = bid & 1023;
  int tk = t >> 5, tn = t & 31;
  const float* src = mat ? Wh : Wx;
  uint16_t* dhi = mat ? wht_hi : wxt_hi;
  uint16_t* dlo = mat ? wht_lo : wxt_lo;
  int tx = threadIdx.x & 31, ty0 = threadIdx.x >> 5;
  int k0 = tk * 32, n0 = tn * 32;
#pragma unroll
  for (int i = 0; i < 4; ++i) {
    int ty = ty0 + 8 * i;
    tile[ty][tx] = src[(size_t)(k0 + ty) * 1024 + n0 + tx];
  }
  __syncthreads();
#pragma unroll
  for (int i = 0; i < 4; ++i) {
    int ty = ty0 + 8 * i;
    float v = tile[tx][ty];                 // = src[k0+tx][n0+ty]
    uint32_t bv = __builtin_bit_cast(uint32_t, v);
    float lo = v - __builtin_bit_cast(float, bv & 0xffff0000u);
    uint32_t lbv = __builtin_bit_cast(uint32_t, lo);
    size_t o = (size_t)(n0 + ty) * 1024 + k0 + tx;   // [n][k]
    dhi[o] = (uint16_t)(bv >> 16);
    dlo[o] = (uint16_t)(lbv >> 16);
  }
}

// ---------------------------------------------------------------------------
// stage 1: out[b*512+s][h] = x @ Wx + b   (split-bf16, 3 terms)
// 128x128 tile, K-step 32, 256 thr (2x2 waves of 64x64), global_load_lds w=16.
// A staged as fp32 (XOR-swizzled), converted to hi/lo in-register.
// B staged as pre-split bf16 from WxT (XOR-swizzled).
// ---------------------------------------------------------------------------
__global__ __launch_bounds__(256) void xw_gemm_kernel(
    const float* __restrict__ x, const uint16_t* __restrict__ wxt_hi,
    const uint16_t* __restrict__ wxt_lo, const float* __restrict__ bias,
    float* __restrict__ out)
{
  __shared__ __align__(16) float    ldsA[128 * 32];     // 16 KB fp32, swizzled
  __shared__ __align__(16) uint16_t ldsBh[128 * 32];    // 8 KB  [n][k] swizzled
  __shared__ __align__(16) uint16_t ldsBl[128 * 32];    // 8 KB

  int bid = blockIdx.x;
  int swz = (bid & 7) * 256 + (bid >> 3);     // XCD-aware (2048 % 8 == 0)
  int mt = swz >> 3, nt = swz & 7;
  int M0 = mt * 128, N0 = nt * 128;

  int tid = threadIdx.x;
  int w = tid >> 6, l = tid & 63;
  int wm = w >> 1, wn = w & 1;

  int a_row = l >> 3;                                   // 0..7 within 8-row group
  int a_sw  = ((l & 7) ^ (l >> 3)) << 4;                // byte swizzle
  int b_row = l >> 2;                                   // 0..15
  int b_sw  = (((l & 3) ^ ((l >> 2) & 3)) << 4);

  f32x4 acc[4][4];
#pragma unroll
  for (int i = 0; i < 4; ++i)
#pragma unroll
    for (int j = 0; j < 4; ++j) acc[i][j] = (f32x4){0.f, 0.f, 0.f, 0.f};

  const char* xb  = (const char*)x;
  const char* bhp = (const char*)wxt_hi;
  const char* blp = (const char*)wxt_lo;

  for (int s = 0; s < 32; ++s) {
    // ---- stage (8 gload_lds / wave) ----
#pragma unroll
    for (int j = 0; j < 4; ++j) {
      int i = 4 * w + j;
      const char* g = xb + ((size_t)(M0 + 8 * i + a_row) * 4096) + s * 128 + a_sw;
      gload_lds16(g, (char*)ldsA + i * 1024);
    }
#pragma unroll
    for (int j = 0; j < 2; ++j) {
      int i = 2 * w + j;
      size_t ro = (size_t)(N0 + 16 * i + b_row) * 2048 + s * 64 + b_sw;
      gload_lds16(bhp + ro, (char*)ldsBh + i * 1024);
      gload_lds16(blp + ro, (char*)ldsBl + i * 1024);
    }
    __syncthreads();   // drains vmcnt -> LDS ready

    // ---- compute ----
    bf16x8 ah[4], al[4], bh[4], bl[4];
#pragma unroll
    for (int mi = 0; mi < 4; ++mi) {
      int row = 64 * wm + 16 * mi + (l & 15);
      int kb  = (l >> 4) * 32;
      int sw  = (row & 7) << 4;
      f32x4 a0 = *(const f32x4*)((const char*)ldsA + row * 128 + (kb ^ sw));
      f32x4 a1 = *(const f32x4*)((const char*)ldsA + row * 128 + ((kb + 16) ^ sw));
      split8(a0, a1, ah[mi], al[mi]);
    }
#pragma unroll
    for (int ni = 0; ni < 4; ++ni) {
      int n  = 64 * wn + 16 * ni + (l & 15);
      int kb = (l >> 4) * 16;
      int off = n * 64 + (kb ^ ((n & 3) << 4));
      bh[ni] = *(const bf16x8*)((const char*)ldsBh + off);
      bl[ni] = *(const bf16x8*)((const char*)ldsBl + off);
    }
#pragma unroll
    for (int mi = 0; mi < 4; ++mi)
#pragma unroll
      for (int ni = 0; ni < 4; ++ni) {
        acc[mi][ni] = mfma16(ah[mi], bh[ni], acc[mi][ni]);
        acc[mi][ni] = mfma16(al[mi], bh[ni], acc[mi][ni]);
        acc[mi][ni] = mfma16(ah[mi], bl[ni], acc[mi][ni]);
      }
    __syncthreads();   // protect LDS before restage
  }

  // ---- epilogue: + bias, store fp32 (this is xw, staged in d_out) ----
#pragma unroll
  for (int ni = 0; ni < 4; ++ni) {
    int col = N0 + 64 * wn + 16 * ni + (l & 15);
    float bv = bias[col];
#pragma unroll
    for (int mi = 0; mi < 4; ++mi) {
      int row0 = M0 + 64 * wm + 16 * mi + 4 * (l >> 4);
#pragma unroll
      for (int r = 0; r < 4; ++r)
        out[(size_t)(row0 + r) * 1024 + col] = acc[mi][ni][r] + bv;
    }
  }
}

// ---------------------------------------------------------------------------
// stage 2: persistent sequential recurrence.
// 32 blocks x 512 thr; block owns 32 cols; Wh slice (hi/lo) in LDS (~128 KB).
// 8 waves = 4 m-tiles x 2 k-halves, LDS reduce. h hi/lo double-buffered in ws.
// Grid barrier: monotonic agent-scope atomic counter, leader arrive/spin.
// ---------------------------------------------------------------------------
__global__ __launch_bounds__(512) void rnn_seq_kernel(
    float* __restrict__ out,
    const uint16_t* __restrict__ wht_hi, const uint16_t* __restrict__ wht_lo,
    uint16_t* __restrict__ hhi, uint16_t* __restrict__ hlo,
    unsigned* __restrict__ cnt)
{
  __shared__ __align__(16) uint16_t WhH[HC][1032];   // [col][k], +8 pad
  __shared__ __align__(16) uint16_t WhL[HC][1032];
  __shared__ __align__(16) float    red[4][64][NI * 4];

  const int tid = threadIdx.x;
  const int c0  = blockIdx.x * HC;

  // preload Wh slice (already transposed+split by prep)
  for (int idx = tid; idx < HC * 128; idx += 512) {
    int rr = idx >> 7, ch = (idx & 127) * 8;
    *(f32x4*)&WhH[rr][ch] = *(const f32x4*)(wht_hi + (size_t)(c0 + rr) * 1024 + ch);
    *(f32x4*)&WhL[rr][ch] = *(const f32x4*)(wht_lo + (size_t)(c0 + rr) * 1024 + ch);
  }
  __syncthreads();

  const int w  = tid >> 6, l = tid & 63;
  const int mi = w & 3, kh = w >> 2;
  const int lr = l & 15, lq = l >> 4;
  const int arow = 16 * mi + lr;       // h row (batch) this lane reads for A
  const int b0   = 16 * mi + 4 * lq;   // first output batch row of D frag
  const int kbase = kh * 512 + lq * 8;
  const int BUFSTR = 64 * 1024;

  for (int t = 0; t < 512; ++t) {
    const int wbuf = t & 1, rbuf = wbuf ^ 1;

    // prefetch xw_t (block-private slice of d_out)
    float xwv[NI][4];
    if (kh == 0) {
#pragma unroll
      for (int n2 = 0; n2 < NI; ++n2)
#pragma unroll
        for (int r = 0; r < 4; ++r)
          xwv[n2][r] = out[((size_t)(b0 + r) * 512 + t) * 1024 + c0 + n2 * 16 + lr];
    }

    f32x4 acc[NI];
#pragma unroll
    for (int n2 = 0; n2 < NI; ++n2) acc[n2] = (f32x4){0.f, 0.f, 0.f, 0.f};

    if (t > 0) {
      const uint16_t* ph  = hhi + rbuf * BUFSTR + (size_t)arow * 1024 + kbase;
      const uint16_t* pl  = hlo + rbuf * BUFSTR + (size_t)arow * 1024 + kbase;
      const uint16_t* q0h = &WhH[lr][kbase];
      const uint16_t* q0l = &WhL[lr][kbase];
      const uint16_t* q1h = &WhH[16 + lr][kbase];
      const uint16_t* q1l = &WhL[16 + lr][kbase];
#pragma unroll 4
      for (int kc = 0; kc < 16; ++kc) {
        bf16x8 ah  = *(const bf16x8*)(ph + kc * 32);
        bf16x8 al  = *(const bf16x8*)(pl + kc * 32);
        bf16x8 b0h = *(const bf16x8*)(q0h + kc * 32);
        bf16x8 b0l = *(const bf16x8*)(q0l + kc * 32);
        bf16x8 b1h = *(const bf16x8*)(q1h + kc * 32);
        bf16x8 b1l = *(const bf16x8*)(q1l + kc * 32);
        acc[0] = mfma16(ah, b0h, acc[0]);
        acc[0] = mfma16(al, b0h, acc[0]);
        acc[0] = mfma16(ah, b0l, acc[0]);
        acc[1] = mfma16(ah, b1h, acc[1]);
        acc[1] = mfma16(al, b1h, acc[1]);
        acc[1] = mfma16(ah, b1l, acc[1]);
      }
    }

    if (kh == 1) {
#pragma unroll
      for (int n2 = 0; n2 < NI; ++n2)
        *(f32x4*)&red[mi][l][n2 * 4] = acc[n2];
    }
    __syncthreads();
    if (kh == 0) {
#pragma unroll
      for (int n2 = 0; n2 < NI; ++n2) {
        f32x4 part = *(const f32x4*)&red[mi][l][n2 * 4];
        acc[n2] += part;
#pragma unroll
        for (int r = 0; r < 4; ++r) {
          const int bb = b0 + r;
          const int colg = c0 + n2 * 16 + lr;
          const size_t oidx = ((size_t)bb * 512 + t) * 1024 + colg;
          float pre = acc[n2][r] + xwv[n2][r];
          float hv = tanhf(pre);
          out[oidx] = hv;
          uint32_t hb = __builtin_bit_cast(uint32_t, hv);
          float lof = hv - __builtin_bit_cast(float, hb & 0xffff0000u);
          uint32_t lb2 = __builtin_bit_cast(uint32_t, lof);
          const size_t hidx = (size_t)wbuf * BUFSTR + (size_t)bb * 1024 + colg;
          hhi[hidx] = (uint16_t)(hb >> 16);
          hlo[hidx] = (uint16_t)(lb2 >> 16);
        }
      }
    }

    if (t < 511) {
      __syncthreads();                 // all waves' stores drained (vmcnt 0)
      if (tid == 0) {
        __threadfence();               // writeback dirty L2 -> device visible
        __hip_atomic_fetch_add(cnt, 1u, __ATOMIC_RELAXED, __HIP_MEMORY_SCOPE_AGENT);
        const unsigned tgt = (unsigned)NBLK2 * (unsigned)(t + 1);
        while (__hip_atomic_load(cnt, __ATOMIC_ACQUIRE, __HIP_MEMORY_SCOPE_AGENT) < tgt)
          __builtin_amdgcn_s_sleep(1);
      }
      __syncthreads();
    }
  }
}

// ---------------------------------------------------------------------------
extern "C" void kernel_launch(void* const* d_in, const int* in_sizes, int n_in,
                              void* d_out, int out_size, void* d_ws, size_t ws_size,
                              hipStream_t stream) {
  const float* x    = (const float*)d_in[0];
  const float* Wx   = (const float*)d_in[1];
  const float* Wh   = (const float*)d_in[2];
  const float* bias = (const float*)d_in[3];
  float* out = (float*)d_out;

  // ws layout (~8.9 MiB): split weights + h double-buffer + barrier counter
  char* ws = (char*)d_ws;
  uint16_t* wxt_hi = (uint16_t*)(ws);
  uint16_t* wxt_lo = (uint16_t*)(ws + (2u << 20));
  uint16_t* wht_hi = (uint16_t*)(ws + (4u << 20));
  uint16_t* wht_lo = (uint16_t*)(ws + (6u << 20));
  uint16_t* hhi    = (uint16_t*)(ws + (8u << 20));
  uint16_t* hlo    = (uint16_t*)(ws + (8u << 20) + (1u << 18));
  unsigned* cnt    = (unsigned*)(ws + (8u << 20) + (2u << 18));

  prep_kernel<<<dim3(2048), dim3(256), 0, stream>>>(Wx, Wh, wxt_hi, wxt_lo,
                                                    wht_hi, wht_lo, cnt);
  xw_gemm_kernel<<<dim3(2048), dim3(256), 0, stream>>>(x, wxt_hi, wxt_lo, bias, out);
  rnn_seq_kernel<<<dim3(NBLK2), dim3(512), 0, stream>>>(out, wht_hi, wht_lo,
                                                        hhi, hlo, cnt);
}